// Round 8
// baseline (312.551 us; speedup 1.0000x reference)
//
#include <hip/hip_runtime.h>
#include <hip/hip_bf16.h>
#include <hip/hip_fp16.h>
#include <string.h>

#define N_NODES 50000
#define N_REL 5
#define N_BASES 5
#define OUT 300
#define N_EDGES 800000
#define NBLK 196               // ceil(N_NODES/256)
#define WU 75                  // fp8x4 dwords per logical W row

// ---- software OCP e4m3fn pack/unpack (no gfx-specific builtins) ----------
// Stored byte v maps to fp16 bits ((v&0x80)<<8)|((v&0x7f)<<7); real = fp16*256.
// The *256 is folded into the mean scale in the consumer.
__device__ __forceinline__ unsigned enc1(float x) {
    unsigned u = (unsigned)__half_as_ushort((__half)(x * 0.00390625f)); // x*2^-8
    unsigned s   = (u >> 15) & 1u;
    unsigned mag = u & 0x7fffu;
    unsigned m8  = (mag + 63u + ((mag >> 7) & 1u)) >> 7;   // RNE drop 7 bits
    return (s << 7) | m8;
}
__device__ __forceinline__ unsigned wenc(float x0, float x1, float x2, float x3) {
    return enc1(x0) | (enc1(x1) << 8) | (enc1(x2) << 16) | (enc1(x3) << 24);
}
__device__ __forceinline__ float2 dec2(unsigned v) {   // bytes 0,1 (scaled 2^-8)
    unsigned h = ((v & 0x80u)   << 8)  | ((v & 0x7fu)   << 7)
               | ((v & 0x8000u) << 16) | ((v & 0x7f00u) << 15);
    __half2 hh;
    memcpy(&hh, &h, 4);
    return __half22float2(hh);
}
__device__ __forceinline__ void wdec(unsigned w, float& x0, float& x1,
                                     float& x2, float& x3) {
    float2 lo = dec2(w);
    float2 hi = dec2(w >> 16);
    x0 = lo.x; x1 = lo.y; x2 = hi.x; x3 = hi.y;
}

// ---- zero int buffer -----------------------------------------------------
__global__ void rgcn_zero(int* __restrict__ p, int n)
{
    int i = blockIdx.x * blockDim.x + threadIdx.x;
    if (i < n) p[i] = 0;
}

// ---- fused: dst histogram + W build (split main/tail tables) -------------
// Wm[t][n][u]  u<64  (cols 4u..4u+3)    -- 256B-aligned rows
// Wt[t][n][v]  v<11  (cols 256+4v..)
__global__ void rgcn_build_w_hist(const float* __restrict__ basis,
                                  const float* __restrict__ comp,
                                  const int* __restrict__ dst,
                                  unsigned* __restrict__ Wm,
                                  unsigned* __restrict__ Wt,
                                  int* __restrict__ deg)
{
    const int gid = blockIdx.x * blockDim.x + threadIdx.x;
    const int gsz = gridDim.x * blockDim.x;

    for (int e = gid; e < N_EDGES; e += gsz)
        atomicAdd(&deg[dst[e]], 1);

    float c[N_REL][N_BASES];
    #pragma unroll
    for (int t = 0; t < N_REL; ++t)
        #pragma unroll
        for (int b = 0; b < N_BASES; ++b)
            c[t][b] = comp[t * N_BASES + b];

    const int total = N_NODES * WU;
    for (int id = gid; id < total; id += gsz) {
        const int n = id / WU;
        const int u = id - n * WU;
        const size_t eoff = (size_t)n * OUT + 4 * u;
        float4 f[N_BASES];
        #pragma unroll
        for (int b = 0; b < N_BASES; ++b)
            f[b] = *(const float4*)&basis[(size_t)b * N_NODES * OUT + eoff];
        #pragma unroll
        for (int t = 0; t < N_REL; ++t) {
            float x0 = 0.f, x1 = 0.f, x2 = 0.f, x3 = 0.f;
            #pragma unroll
            for (int b = 0; b < N_BASES; ++b) {
                x0 += c[t][b] * f[b].x; x1 += c[t][b] * f[b].y;
                x2 += c[t][b] * f[b].z; x3 += c[t][b] * f[b].w;
            }
            const unsigned w = wenc(x0, x1, x2, x3);
            if (u < 64) Wm[(size_t)t * N_NODES * 64 + (size_t)n * 64 + u] = w;
            else        Wt[(size_t)t * N_NODES * 11 + (size_t)n * 11 + (u - 64)] = w;
        }
    }
}

// ---- scanA: blockwise exclusive scan of deg ------------------------------
__global__ void rgcn_scanA(const int* __restrict__ deg, int* __restrict__ part,
                           int* __restrict__ bsum)
{
    __shared__ int sm[256];
    const int i = blockIdx.x * 256 + (int)threadIdx.x;
    const int v = (i < N_NODES) ? deg[i] : 0;
    sm[threadIdx.x] = v;
    __syncthreads();
    for (int off = 1; off < 256; off <<= 1) {
        int t = (threadIdx.x >= (unsigned)off) ? sm[threadIdx.x - off] : 0;
        __syncthreads();
        sm[threadIdx.x] += t;
        __syncthreads();
    }
    if (i < N_NODES) part[i] = sm[threadIdx.x] - v;          // exclusive in block
    if (threadIdx.x == 255) bsum[blockIdx.x] = sm[255];
}

// ---- scanBC: idempotent -- reads part+bsum, writes offsF and cursor ------
__global__ void rgcn_scanBC(const int* __restrict__ part,
                            const int* __restrict__ bsum,
                            int* __restrict__ offsF,
                            int* __restrict__ cursor)
{
    __shared__ int sm[256];
    __shared__ int prefix_s;
    const int v = (threadIdx.x < NBLK) ? bsum[threadIdx.x] : 0;
    sm[threadIdx.x] = v;
    __syncthreads();
    for (int off = 1; off < 256; off <<= 1) {
        int t = (threadIdx.x >= (unsigned)off) ? sm[threadIdx.x - off] : 0;
        __syncthreads();
        sm[threadIdx.x] += t;
        __syncthreads();
    }
    if (threadIdx.x == blockIdx.x) prefix_s = sm[threadIdx.x] - v;  // exclusive
    __syncthreads();
    const int prefix = prefix_s;
    const int i = blockIdx.x * 256 + (int)threadIdx.x;
    if (i < N_NODES) {
        const int o = part[i] + prefix;
        offsF[i] = o;
        cursor[i] = o;
    }
    if (i == 0) offsF[N_NODES] = N_EDGES;
}

// ---- scatter edges into dst-sorted order, packed (t<<16)|src -------------
__global__ void rgcn_scatter(const int* __restrict__ srcA,
                             const int* __restrict__ dstA,
                             const int* __restrict__ typeA,
                             int* __restrict__ cursor,
                             int* __restrict__ sorted)
{
    for (int e = blockIdx.x * blockDim.x + threadIdx.x; e < N_EDGES;
         e += gridDim.x * blockDim.x) {
        const int d = dstA[e];
        const int pos = atomicAdd(&cursor[d], 1);
        sorted[pos] = srcA[e] | (typeA[e] << 16);   // src < 65536, t < 8
    }
}

// ---- aggregate + mean + root + bias + relu + log_softmax, 1 wave/node ----
// Identical to round 7 (8-edge pipelined batches). Launched TWICE this round
// (idempotent) so dur_us_delta vs round 7 measures its exact cost.
__global__ __launch_bounds__(256) void rgcn_aggregate(
    const int* __restrict__ offs, const int* __restrict__ sorted,
    const unsigned* __restrict__ Wm, const unsigned* __restrict__ Wt,
    const float* __restrict__ root, const float* __restrict__ bias,
    float* __restrict__ out)
{
    const int lane = (int)(threadIdx.x & 63);
    const int k    = lane & 15;
    const int g    = lane >> 4;
    const bool ktail = k < 11;
    const int node = blockIdx.x * 4 + (int)(threadIdx.x >> 6);
    if (node >= N_NODES) return;
    const int s = offs[node];
    const int e_end = offs[node + 1];
    const int deg = e_end - s;

    float a0=0.f,a1=0.f,a2=0.f,a3=0.f;
    float t0=0.f,t1=0.f,t2=0.f,t3=0.f;
    float x0, x1, x2, x3;
    int i = s;

    const int nb8 = deg >> 3;
    if (nb8 > 0) {
        unsigned cw[8], nw[8];
        unsigned ct0, ct1, nt0, nt1;
        {
            unsigned r[8];
            #pragma unroll
            for (int j = 0; j < 8; ++j) {
                const int p = sorted[i + j];
                r[j] = (unsigned)(p >> 16) * N_NODES + (p & 0xFFFF);
            }
            #pragma unroll
            for (int j = 0; j < 8; ++j) cw[j] = Wm[r[j] * 64u + lane];
            const unsigned rg0 = (g == 0) ? r[0] : (g == 1) ? r[1] : (g == 2) ? r[2] : r[3];
            const unsigned rg1 = (g == 0) ? r[4] : (g == 1) ? r[5] : (g == 2) ? r[6] : r[7];
            ct0 = ktail ? Wt[rg0 * 11u + (unsigned)k] : 0u;
            ct1 = ktail ? Wt[rg1 * 11u + (unsigned)k] : 0u;
        }
        for (int b = 1; b < nb8; ++b) {
            i += 8;
            unsigned r[8];
            #pragma unroll
            for (int j = 0; j < 8; ++j) {
                const int p = sorted[i + j];
                r[j] = (unsigned)(p >> 16) * N_NODES + (p & 0xFFFF);
            }
            #pragma unroll
            for (int j = 0; j < 8; ++j) nw[j] = Wm[r[j] * 64u + lane];
            const unsigned rg0 = (g == 0) ? r[0] : (g == 1) ? r[1] : (g == 2) ? r[2] : r[3];
            const unsigned rg1 = (g == 0) ? r[4] : (g == 1) ? r[5] : (g == 2) ? r[6] : r[7];
            nt0 = ktail ? Wt[rg0 * 11u + (unsigned)k] : 0u;
            nt1 = ktail ? Wt[rg1 * 11u + (unsigned)k] : 0u;
            #pragma unroll
            for (int j = 0; j < 8; ++j) {
                wdec(cw[j], x0, x1, x2, x3);
                a0 += x0; a1 += x1; a2 += x2; a3 += x3;
            }
            wdec(ct0, x0, x1, x2, x3); t0 += x0; t1 += x1; t2 += x2; t3 += x3;
            wdec(ct1, x0, x1, x2, x3); t0 += x0; t1 += x1; t2 += x2; t3 += x3;
            #pragma unroll
            for (int j = 0; j < 8; ++j) cw[j] = nw[j];
            ct0 = nt0; ct1 = nt1;
        }
        #pragma unroll
        for (int j = 0; j < 8; ++j) {
            wdec(cw[j], x0, x1, x2, x3);
            a0 += x0; a1 += x1; a2 += x2; a3 += x3;
        }
        wdec(ct0, x0, x1, x2, x3); t0 += x0; t1 += x1; t2 += x2; t3 += x3;
        wdec(ct1, x0, x1, x2, x3); t0 += x0; t1 += x1; t2 += x2; t3 += x3;
        i += 8;
    }

    for (; i + 3 < e_end; i += 4) {
        const int p0 = sorted[i],     p1 = sorted[i + 1];
        const int p2 = sorted[i + 2], p3 = sorted[i + 3];
        const unsigned r0 = (unsigned)(p0 >> 16) * N_NODES + (p0 & 0xFFFF);
        const unsigned r1 = (unsigned)(p1 >> 16) * N_NODES + (p1 & 0xFFFF);
        const unsigned r2 = (unsigned)(p2 >> 16) * N_NODES + (p2 & 0xFFFF);
        const unsigned r3 = (unsigned)(p3 >> 16) * N_NODES + (p3 & 0xFFFF);
        const unsigned w0 = Wm[r0 * 64u + lane];
        const unsigned w1 = Wm[r1 * 64u + lane];
        const unsigned w2 = Wm[r2 * 64u + lane];
        const unsigned w3 = Wm[r3 * 64u + lane];
        const unsigned rg = (g == 0) ? r0 : (g == 1) ? r1 : (g == 2) ? r2 : r3;
        unsigned wt = 0;
        if (ktail) wt = Wt[rg * 11u + (unsigned)k];
        wdec(w0, x0, x1, x2, x3); a0 += x0; a1 += x1; a2 += x2; a3 += x3;
        wdec(w1, x0, x1, x2, x3); a0 += x0; a1 += x1; a2 += x2; a3 += x3;
        wdec(w2, x0, x1, x2, x3); a0 += x0; a1 += x1; a2 += x2; a3 += x3;
        wdec(w3, x0, x1, x2, x3); a0 += x0; a1 += x1; a2 += x2; a3 += x3;
        wdec(wt, x0, x1, x2, x3); t0 += x0; t1 += x1; t2 += x2; t3 += x3;
    }
    for (; i < e_end; ++i) {
        const int p0 = sorted[i];
        const unsigned r0 = (unsigned)(p0 >> 16) * N_NODES + (p0 & 0xFFFF);
        const unsigned w0 = Wm[r0 * 64u + lane];
        unsigned wt = 0;
        if (lane < 11) wt = Wt[r0 * 11u + (unsigned)lane];   // g=0, k=lane
        wdec(w0, x0, x1, x2, x3); a0 += x0; a1 += x1; a2 += x2; a3 += x3;
        wdec(wt, x0, x1, x2, x3); t0 += x0; t1 += x1; t2 += x2; t3 += x3;
    }

    // reduce tail accumulators across the 4 lane-groups (same k -> same cols)
    t0 += __shfl_down(t0, 32, 64); t1 += __shfl_down(t1, 32, 64);
    t2 += __shfl_down(t2, 32, 64); t3 += __shfl_down(t3, 32, 64);
    t0 += __shfl_down(t0, 16, 64); t1 += __shfl_down(t1, 16, 64);
    t2 += __shfl_down(t2, 16, 64); t3 += __shfl_down(t3, 16, 64);
    const bool tail = lane < 11;   // valid tail sums now live in lanes 0..10

    // *256 undoes the fp8 storage scale (decode yields value*2^-8)
    const float inv = 256.0f / fmaxf((float)deg, 1.0f);
    const size_t ro = (size_t)node * OUT;
    const float4 rt0 = *(const float4*)&root[ro + 4 * lane];
    const float4 bi0 = *(const float4*)&bias[4 * lane];
    float v0 = fmaxf(a0 * inv + rt0.x + bi0.x, 0.0f);
    float v1 = fmaxf(a1 * inv + rt0.y + bi0.y, 0.0f);
    float v2 = fmaxf(a2 * inv + rt0.z + bi0.z, 0.0f);
    float v3 = fmaxf(a3 * inv + rt0.w + bi0.w, 0.0f);
    float v4 = 0.f, v5 = 0.f, v6 = 0.f, v7 = 0.f;
    if (tail) {
        const float4 rt1 = *(const float4*)&root[ro + 256 + 4 * lane];
        const float4 bi1 = *(const float4*)&bias[256 + 4 * lane];
        v4 = fmaxf(t0 * inv + rt1.x + bi1.x, 0.0f);
        v5 = fmaxf(t1 * inv + rt1.y + bi1.y, 0.0f);
        v6 = fmaxf(t2 * inv + rt1.z + bi1.z, 0.0f);
        v7 = fmaxf(t3 * inv + rt1.w + bi1.w, 0.0f);
    }
    // relu >= 0 so zero-initialized invalid slots are safe for max
    float m = fmaxf(fmaxf(fmaxf(v0, v1), fmaxf(v2, v3)),
                    fmaxf(fmaxf(v4, v5), fmaxf(v6, v7)));
    #pragma unroll
    for (int off = 32; off >= 1; off >>= 1) m = fmaxf(m, __shfl_xor(m, off, 64));
    float sum = __expf(v0 - m) + __expf(v1 - m) + __expf(v2 - m) + __expf(v3 - m);
    if (tail) sum += __expf(v4 - m) + __expf(v5 - m) + __expf(v6 - m) + __expf(v7 - m);
    #pragma unroll
    for (int off = 32; off >= 1; off >>= 1) sum += __shfl_xor(sum, off, 64);
    const float lse = m + logf(sum);
    *(float4*)&out[ro + 4 * lane] =
        make_float4(v0 - lse, v1 - lse, v2 - lse, v3 - lse);
    if (tail)
        *(float4*)&out[ro + 256 + 4 * lane] =
            make_float4(v4 - lse, v5 - lse, v6 - lse, v7 - lse);
}

// ===========================================================================
// Fallback path (round-1 kernels) if ws_size is too small
// ===========================================================================
__global__ void rgcn_edge_scatter(const int* __restrict__ edge_index,
                                  const int* __restrict__ edge_type,
                                  const float* __restrict__ basis,
                                  const float* __restrict__ comp,
                                  float* __restrict__ agg,
                                  float* __restrict__ cnt)
{
    const int lane = threadIdx.x & 63;
    const int wid  = (blockIdx.x * (blockDim.x >> 6)) + (threadIdx.x >> 6);
    const int nwav = gridDim.x * (blockDim.x >> 6);
    const int* __restrict__ src_arr = edge_index;
    const int* __restrict__ dst_arr = edge_index + N_EDGES;
    for (int e = wid; e < N_EDGES; e += nwav) {
        const int src = src_arr[e];
        const int dst = dst_arr[e];
        const int t   = edge_type[e];
        const float c0 = comp[t*N_BASES+0], c1 = comp[t*N_BASES+1],
                    c2 = comp[t*N_BASES+2], c3 = comp[t*N_BASES+3],
                    c4 = comp[t*N_BASES+4];
        const size_t rowoff = (size_t)src * OUT;
        const float* b0 = basis + rowoff;
        const float* b1 = basis + (size_t)1*N_NODES*OUT + rowoff;
        const float* b2 = basis + (size_t)2*N_NODES*OUT + rowoff;
        const float* b3 = basis + (size_t)3*N_NODES*OUT + rowoff;
        const float* b4 = basis + (size_t)4*N_NODES*OUT + rowoff;
        float* aout = agg + (size_t)dst * OUT;
        for (int d = lane; d < OUT; d += 64) {
            float m = c0*b0[d] + c1*b1[d] + c2*b2[d] + c3*b3[d] + c4*b4[d];
            atomicAdd(&aout[d], m);
        }
        if (lane == 0) atomicAdd(&cnt[dst], 1.0f);
    }
}

__global__ void rgcn_finalize(float* __restrict__ agg,
                              const float* __restrict__ cnt,
                              const float* __restrict__ root,
                              const float* __restrict__ bias)
{
    const int lane = threadIdx.x & 63;
    const int wid  = (blockIdx.x * (blockDim.x >> 6)) + (threadIdx.x >> 6);
    if (wid >= N_NODES) return;
    const size_t rowoff = (size_t)wid * OUT;
    const float inv = 1.0f / fmaxf(cnt[wid], 1.0f);
    float v[5];
    float lmax = 0.0f;
    #pragma unroll
    for (int kk = 0; kk < 5; ++kk) {
        int d = lane + kk * 64;
        if (d < OUT) {
            float h = agg[rowoff + d] * inv + root[rowoff + d] + bias[d];
            float r = fmaxf(h, 0.0f);
            v[kk] = r; lmax = fmaxf(lmax, r);
        } else v[kk] = 0.0f;
    }
    #pragma unroll
    for (int off = 32; off >= 1; off >>= 1) lmax = fmaxf(lmax, __shfl_xor(lmax, off, 64));
    float lsum = 0.0f;
    #pragma unroll
    for (int kk = 0; kk < 5; ++kk) { int d = lane + kk*64; if (d < OUT) lsum += __expf(v[kk]-lmax); }
    #pragma unroll
    for (int off = 32; off >= 1; off >>= 1) lsum += __shfl_xor(lsum, off, 64);
    const float lse = lmax + logf(lsum);
    #pragma unroll
    for (int kk = 0; kk < 5; ++kk) { int d = lane + kk*64; if (d < OUT) agg[rowoff+d] = v[kk]-lse; }
}

// ===========================================================================
extern "C" void kernel_launch(void* const* d_in, const int* in_sizes, int n_in,
                              void* d_out, int out_size, void* d_ws, size_t ws_size,
                              hipStream_t stream) {
    const int*   edge_index = (const int*)d_in[0];   // [2, E]
    const int*   edge_type  = (const int*)d_in[1];   // [E]
    const float* basis      = (const float*)d_in[3]; // [B, N, OUT]
    const float* comp       = (const float*)d_in[4]; // [R, B]
    const float* root       = (const float*)d_in[5]; // [N, OUT]
    const float* bias       = (const float*)d_in[6]; // [OUT]

    // ws layout (aligned)
    const size_t o_part   = 0;            // int[N]   (scanA partial)
    const size_t o_cursor = 200192;       // int[N]   (deg, then scatter cursor)
    const size_t o_bsum   = 400384;       // int[256]
    const size_t o_offsF  = 401408;       // int[N+1] (final offsets)
    const size_t o_sorted = 601600;       // int[E]
    const size_t o_Wm     = 3801600;      // unsigned[5*N*64] = 64 MB (256B rows)
    const size_t o_Wt     = 67801600;     // unsigned[5*N*11] = 11 MB
    const size_t need     = o_Wt + (size_t)N_REL * N_NODES * 11 * sizeof(unsigned);

    if (ws_size >= need) {
        int*      part   = (int*)((char*)d_ws + o_part);
        int*      cursor = (int*)((char*)d_ws + o_cursor);
        int*      bsum   = (int*)((char*)d_ws + o_bsum);
        int*      offsF  = (int*)((char*)d_ws + o_offsF);
        int*      sorted = (int*)((char*)d_ws + o_sorted);
        unsigned* Wm     = (unsigned*)((char*)d_ws + o_Wm);
        unsigned* Wt     = (unsigned*)((char*)d_ws + o_Wt);

        rgcn_zero<<<NBLK, 256, 0, stream>>>(cursor, N_NODES);
        rgcn_build_w_hist<<<8192, 256, 0, stream>>>(basis, comp,
                                                    edge_index + N_EDGES,
                                                    Wm, Wt, cursor);
        rgcn_scanA<<<NBLK, 256, 0, stream>>>(cursor, part, bsum);
        rgcn_scanBC<<<NBLK, 256, 0, stream>>>(part, bsum, offsF, cursor);
        rgcn_scatter<<<1024, 256, 0, stream>>>(edge_index, edge_index + N_EDGES,
                                               edge_type, cursor, sorted);
        // Launched twice (idempotent): dur_us delta vs round 7 = aggregate cost.
        rgcn_aggregate<<<(N_NODES + 3) / 4, 256, 0, stream>>>(
            offsF, sorted, Wm, Wt, root, bias, (float*)d_out);
        rgcn_aggregate<<<(N_NODES + 3) / 4, 256, 0, stream>>>(
            offsF, sorted, Wm, Wt, root, bias, (float*)d_out);
    } else {
        float* agg = (float*)d_out;
        float* cnt = (float*)d_ws;
        hipMemsetAsync(agg, 0, (size_t)out_size * sizeof(float), stream);
        hipMemsetAsync(cnt, 0, (size_t)N_NODES * sizeof(float), stream);
        rgcn_edge_scatter<<<4096, 256, 0, stream>>>(edge_index, edge_type, basis,
                                                    comp, agg, cnt);
        const int blocks = (N_NODES + 3) / 4;
        rgcn_finalize<<<blocks, 256, 0, stream>>>(agg, cnt, root, bias);
    }
}

// Round 9
// 237.254 us; speedup vs baseline: 1.3174x; 1.3174x over previous
//
#include <hip/hip_runtime.h>
#include <hip/hip_bf16.h>
#include <hip/hip_fp16.h>
#include <string.h>

#define N_NODES 50000
#define N_REL 5
#define N_BASES 5
#define OUT 300
#define N_EDGES 800000
#define NBLK 196               // ceil(N_NODES/256)
#define WU 75                  // fp8x4 dwords per logical W row

// ---- software OCP e4m3fn pack/unpack (no gfx-specific builtins) ----------
// Stored byte v maps to fp16 bits ((v&0x80)<<8)|((v&0x7f)<<7); real = fp16*256.
// The *256 is folded into the mean scale in the consumer.
__device__ __forceinline__ unsigned enc1(float x) {
    unsigned u = (unsigned)__half_as_ushort((__half)(x * 0.00390625f)); // x*2^-8
    unsigned s   = (u >> 15) & 1u;
    unsigned mag = u & 0x7fffu;
    unsigned m8  = (mag + 63u + ((mag >> 7) & 1u)) >> 7;   // RNE drop 7 bits
    return (s << 7) | m8;
}
__device__ __forceinline__ unsigned wenc(float x0, float x1, float x2, float x3) {
    return enc1(x0) | (enc1(x1) << 8) | (enc1(x2) << 16) | (enc1(x3) << 24);
}
__device__ __forceinline__ float2 dec2(unsigned v) {   // bytes 0,1 (scaled 2^-8)
    unsigned h = ((v & 0x80u)   << 8)  | ((v & 0x7fu)   << 7)
               | ((v & 0x8000u) << 16) | ((v & 0x7f00u) << 15);
    __half2 hh;
    memcpy(&hh, &h, 4);
    return __half22float2(hh);
}
__device__ __forceinline__ void wdec(unsigned w, float& x0, float& x1,
                                     float& x2, float& x3) {
    float2 lo = dec2(w);
    float2 hi = dec2(w >> 16);
    x0 = lo.x; x1 = lo.y; x2 = hi.x; x3 = hi.y;
}

// ---- zero int buffer -----------------------------------------------------
__global__ void rgcn_zero(int* __restrict__ p, int n)
{
    int i = blockIdx.x * blockDim.x + threadIdx.x;
    if (i < n) p[i] = 0;
}

// ---- fused: dst histogram + W build (split main/tail tables) -------------
// Wm[t][n][u]  u<64  (cols 4u..4u+3)    -- 256B-aligned rows
// Wt[t][n][v]  v<11  (cols 256+4v..)
// Grid sized so the grid-stride loop runs exactly ~2.0 balanced passes.
__global__ void rgcn_build_w_hist(const float* __restrict__ basis,
                                  const float* __restrict__ comp,
                                  const int* __restrict__ dst,
                                  unsigned* __restrict__ Wm,
                                  unsigned* __restrict__ Wt,
                                  int* __restrict__ deg)
{
    const int gid = blockIdx.x * blockDim.x + threadIdx.x;
    const int gsz = gridDim.x * blockDim.x;

    for (int e = gid; e < N_EDGES; e += gsz)
        atomicAdd(&deg[dst[e]], 1);

    float c[N_REL][N_BASES];
    #pragma unroll
    for (int t = 0; t < N_REL; ++t)
        #pragma unroll
        for (int b = 0; b < N_BASES; ++b)
            c[t][b] = comp[t * N_BASES + b];

    const int total = N_NODES * WU;
    for (int id = gid; id < total; id += gsz) {
        const int n = id / WU;
        const int u = id - n * WU;
        const size_t eoff = (size_t)n * OUT + 4 * u;
        float4 f[N_BASES];
        #pragma unroll
        for (int b = 0; b < N_BASES; ++b)
            f[b] = *(const float4*)&basis[(size_t)b * N_NODES * OUT + eoff];
        #pragma unroll
        for (int t = 0; t < N_REL; ++t) {
            float x0 = 0.f, x1 = 0.f, x2 = 0.f, x3 = 0.f;
            #pragma unroll
            for (int b = 0; b < N_BASES; ++b) {
                x0 += c[t][b] * f[b].x; x1 += c[t][b] * f[b].y;
                x2 += c[t][b] * f[b].z; x3 += c[t][b] * f[b].w;
            }
            const unsigned w = wenc(x0, x1, x2, x3);
            if (u < 64) Wm[(size_t)t * N_NODES * 64 + (size_t)n * 64 + u] = w;
            else        Wt[(size_t)t * N_NODES * 11 + (size_t)n * 11 + (u - 64)] = w;
        }
    }
}

// ---- scanA: blockwise exclusive scan of deg ------------------------------
__global__ void rgcn_scanA(const int* __restrict__ deg, int* __restrict__ part,
                           int* __restrict__ bsum)
{
    __shared__ int sm[256];
    const int i = blockIdx.x * 256 + (int)threadIdx.x;
    const int v = (i < N_NODES) ? deg[i] : 0;
    sm[threadIdx.x] = v;
    __syncthreads();
    for (int off = 1; off < 256; off <<= 1) {
        int t = (threadIdx.x >= (unsigned)off) ? sm[threadIdx.x - off] : 0;
        __syncthreads();
        sm[threadIdx.x] += t;
        __syncthreads();
    }
    if (i < N_NODES) part[i] = sm[threadIdx.x] - v;          // exclusive in block
    if (threadIdx.x == 255) bsum[blockIdx.x] = sm[255];
}

// ---- scanBC: idempotent -- reads part+bsum, writes offsF and cursor ------
__global__ void rgcn_scanBC(const int* __restrict__ part,
                            const int* __restrict__ bsum,
                            int* __restrict__ offsF,
                            int* __restrict__ cursor)
{
    __shared__ int sm[256];
    __shared__ int prefix_s;
    const int v = (threadIdx.x < NBLK) ? bsum[threadIdx.x] : 0;
    sm[threadIdx.x] = v;
    __syncthreads();
    for (int off = 1; off < 256; off <<= 1) {
        int t = (threadIdx.x >= (unsigned)off) ? sm[threadIdx.x - off] : 0;
        __syncthreads();
        sm[threadIdx.x] += t;
        __syncthreads();
    }
    if (threadIdx.x == blockIdx.x) prefix_s = sm[threadIdx.x] - v;  // exclusive
    __syncthreads();
    const int prefix = prefix_s;
    const int i = blockIdx.x * 256 + (int)threadIdx.x;
    if (i < N_NODES) {
        const int o = part[i] + prefix;
        offsF[i] = o;
        cursor[i] = o;
    }
    if (i == 0) offsF[N_NODES] = N_EDGES;
}

// ---- scatter edges into dst-sorted order, packed (t<<16)|src -------------
__global__ void rgcn_scatter(const int* __restrict__ srcA,
                             const int* __restrict__ dstA,
                             const int* __restrict__ typeA,
                             int* __restrict__ cursor,
                             int* __restrict__ sorted)
{
    for (int e = blockIdx.x * blockDim.x + threadIdx.x; e < N_EDGES;
         e += gridDim.x * blockDim.x) {
        const int d = dstA[e];
        const int pos = atomicAdd(&cursor[d], 1);
        sorted[pos] = srcA[e] | (typeA[e] << 16);   // src < 65536, t < 8
    }
}

// ---- aggregate + mean + root + bias + relu + log_softmax, 1 wave/node ----
// Transposed gather: lane l = 16g+k; group g takes edge i+g; lane-sixteenth k
// loads uint4 = cols [16k..16k+15]. One dwordx4 instr covers 4 edges (4x256B
// coalesced) -> 3 VMEM instrs per 4 edges (vs 9 before). Cross-group
// shfl_down(32,16) reduce, LDS handoff, then the proven per-lane epilogue.
__global__ __launch_bounds__(256) void rgcn_aggregate(
    const int* __restrict__ offs, const int* __restrict__ sorted,
    const unsigned* __restrict__ Wm, const unsigned* __restrict__ Wt,
    const float* __restrict__ root, const float* __restrict__ bias,
    float* __restrict__ out)
{
    __shared__ float smrow[4][304];
    const int lane = (int)(threadIdx.x & 63);
    const int wid  = (int)(threadIdx.x >> 6);
    const int k    = lane & 15;          // column-sixteenth
    const int g    = lane >> 4;          // edge group
    const int node = blockIdx.x * 4 + wid;   // grid is exact: 12500*4 = 50000
    const int s = offs[node];
    const int e_end = offs[node + 1];
    const int deg = e_end - s;
    const bool ktail = k < 11;

    float a[16];
    #pragma unroll
    for (int j = 0; j < 16; ++j) a[j] = 0.f;
    float t0 = 0.f, t1 = 0.f, t2 = 0.f, t3 = 0.f;

    const int nb4 = (deg + 3) >> 2;
    for (int bi = 0; bi < nb4; ++bi) {
        const int eidx = s + (bi << 2) + g;
        const bool act = eidx < e_end;
        const int p = sorted[act ? eidx : s];
        const unsigned r = (unsigned)(p >> 16) * N_NODES + (p & 0xFFFF);
        const uint4 w = *(const uint4*)&Wm[r * 64u + 4u * (unsigned)k];
        unsigned wt = 0u;
        if (ktail) wt = Wt[r * 11u + (unsigned)k];
        if (act) {
            float x0, x1, x2, x3;
            wdec(w.x, x0,x1,x2,x3); a[0]+=x0;  a[1]+=x1;  a[2]+=x2;  a[3]+=x3;
            wdec(w.y, x0,x1,x2,x3); a[4]+=x0;  a[5]+=x1;  a[6]+=x2;  a[7]+=x3;
            wdec(w.z, x0,x1,x2,x3); a[8]+=x0;  a[9]+=x1;  a[10]+=x2; a[11]+=x3;
            wdec(w.w, x0,x1,x2,x3); a[12]+=x0; a[13]+=x1; a[14]+=x2; a[15]+=x3;
            wdec(wt,  x0,x1,x2,x3); t0+=x0;    t1+=x1;    t2+=x2;    t3+=x3;
        }
    }

    // reduce across the 4 edge-groups (same columns, different edges)
    #pragma unroll
    for (int j = 0; j < 16; ++j) {
        a[j] += __shfl_down(a[j], 32, 64);
        a[j] += __shfl_down(a[j], 16, 64);
    }
    t0 += __shfl_down(t0, 32, 64); t1 += __shfl_down(t1, 32, 64);
    t2 += __shfl_down(t2, 32, 64); t3 += __shfl_down(t3, 32, 64);
    t0 += __shfl_down(t0, 16, 64); t1 += __shfl_down(t1, 16, 64);
    t2 += __shfl_down(t2, 16, 64); t3 += __shfl_down(t3, 16, 64);

    // lanes 0..15 hold cols [16k..16k+15]; lanes 0..10 hold tail cols.
    if (lane < 16) {
        #pragma unroll
        for (int q = 0; q < 4; ++q) {
            float4 f4 = make_float4(a[4*q+0], a[4*q+1], a[4*q+2], a[4*q+3]);
            *(float4*)&smrow[wid][16 * lane + 4 * q] = f4;
        }
    }
    if (lane < 11)
        *(float4*)&smrow[wid][256 + 4 * lane] = make_float4(t0, t1, t2, t3);
    __syncthreads();

    // proven epilogue: lane l owns cols [4l..4l+3] (+ tail for l<11)
    const float4 aa = *(const float4*)&smrow[wid][4 * lane];
    const bool tail = lane < 11;
    float4 tt = make_float4(0.f, 0.f, 0.f, 0.f);
    if (tail) tt = *(const float4*)&smrow[wid][256 + 4 * lane];

    // *256 undoes the fp8 storage scale (decode yields value*2^-8)
    const float inv = 256.0f / fmaxf((float)deg, 1.0f);
    const size_t ro = (size_t)node * OUT;
    const float4 rt0 = *(const float4*)&root[ro + 4 * lane];
    const float4 bi0 = *(const float4*)&bias[4 * lane];
    float v0 = fmaxf(aa.x * inv + rt0.x + bi0.x, 0.0f);
    float v1 = fmaxf(aa.y * inv + rt0.y + bi0.y, 0.0f);
    float v2 = fmaxf(aa.z * inv + rt0.z + bi0.z, 0.0f);
    float v3 = fmaxf(aa.w * inv + rt0.w + bi0.w, 0.0f);
    float v4 = 0.f, v5 = 0.f, v6 = 0.f, v7 = 0.f;
    if (tail) {
        const float4 rt1 = *(const float4*)&root[ro + 256 + 4 * lane];
        const float4 bi1 = *(const float4*)&bias[256 + 4 * lane];
        v4 = fmaxf(tt.x * inv + rt1.x + bi1.x, 0.0f);
        v5 = fmaxf(tt.y * inv + rt1.y + bi1.y, 0.0f);
        v6 = fmaxf(tt.z * inv + rt1.z + bi1.z, 0.0f);
        v7 = fmaxf(tt.w * inv + rt1.w + bi1.w, 0.0f);
    }
    // relu >= 0 so zero-initialized invalid slots are safe for max
    float m = fmaxf(fmaxf(fmaxf(v0, v1), fmaxf(v2, v3)),
                    fmaxf(fmaxf(v4, v5), fmaxf(v6, v7)));
    #pragma unroll
    for (int off = 32; off >= 1; off >>= 1) m = fmaxf(m, __shfl_xor(m, off, 64));
    float sum = __expf(v0 - m) + __expf(v1 - m) + __expf(v2 - m) + __expf(v3 - m);
    if (tail) sum += __expf(v4 - m) + __expf(v5 - m) + __expf(v6 - m) + __expf(v7 - m);
    #pragma unroll
    for (int off = 32; off >= 1; off >>= 1) sum += __shfl_xor(sum, off, 64);
    const float lse = m + logf(sum);
    *(float4*)&out[ro + 4 * lane] =
        make_float4(v0 - lse, v1 - lse, v2 - lse, v3 - lse);
    if (tail)
        *(float4*)&out[ro + 256 + 4 * lane] =
            make_float4(v4 - lse, v5 - lse, v6 - lse, v7 - lse);
}

// ===========================================================================
// Fallback path (round-1 kernels) if ws_size is too small
// ===========================================================================
__global__ void rgcn_edge_scatter(const int* __restrict__ edge_index,
                                  const int* __restrict__ edge_type,
                                  const float* __restrict__ basis,
                                  const float* __restrict__ comp,
                                  float* __restrict__ agg,
                                  float* __restrict__ cnt)
{
    const int lane = threadIdx.x & 63;
    const int wid  = (blockIdx.x * (blockDim.x >> 6)) + (threadIdx.x >> 6);
    const int nwav = gridDim.x * (blockDim.x >> 6);
    const int* __restrict__ src_arr = edge_index;
    const int* __restrict__ dst_arr = edge_index + N_EDGES;
    for (int e = wid; e < N_EDGES; e += nwav) {
        const int src = src_arr[e];
        const int dst = dst_arr[e];
        const int t   = edge_type[e];
        const float c0 = comp[t*N_BASES+0], c1 = comp[t*N_BASES+1],
                    c2 = comp[t*N_BASES+2], c3 = comp[t*N_BASES+3],
                    c4 = comp[t*N_BASES+4];
        const size_t rowoff = (size_t)src * OUT;
        const float* b0 = basis + rowoff;
        const float* b1 = basis + (size_t)1*N_NODES*OUT + rowoff;
        const float* b2 = basis + (size_t)2*N_NODES*OUT + rowoff;
        const float* b3 = basis + (size_t)3*N_NODES*OUT + rowoff;
        const float* b4 = basis + (size_t)4*N_NODES*OUT + rowoff;
        float* aout = agg + (size_t)dst * OUT;
        for (int d = lane; d < OUT; d += 64) {
            float m = c0*b0[d] + c1*b1[d] + c2*b2[d] + c3*b3[d] + c4*b4[d];
            atomicAdd(&aout[d], m);
        }
        if (lane == 0) atomicAdd(&cnt[dst], 1.0f);
    }
}

__global__ void rgcn_finalize(float* __restrict__ agg,
                              const float* __restrict__ cnt,
                              const float* __restrict__ root,
                              const float* __restrict__ bias)
{
    const int lane = threadIdx.x & 63;
    const int wid  = (blockIdx.x * (blockDim.x >> 6)) + (threadIdx.x >> 6);
    if (wid >= N_NODES) return;
    const size_t rowoff = (size_t)wid * OUT;
    const float inv = 1.0f / fmaxf(cnt[wid], 1.0f);
    float v[5];
    float lmax = 0.0f;
    #pragma unroll
    for (int kk = 0; kk < 5; ++kk) {
        int d = lane + kk * 64;
        if (d < OUT) {
            float h = agg[rowoff + d] * inv + root[rowoff + d] + bias[d];
            float r = fmaxf(h, 0.0f);
            v[kk] = r; lmax = fmaxf(lmax, r);
        } else v[kk] = 0.0f;
    }
    #pragma unroll
    for (int off = 32; off >= 1; off >>= 1) lmax = fmaxf(lmax, __shfl_xor(lmax, off, 64));
    float lsum = 0.0f;
    #pragma unroll
    for (int kk = 0; kk < 5; ++kk) { int d = lane + kk*64; if (d < OUT) lsum += __expf(v[kk]-lmax); }
    #pragma unroll
    for (int off = 32; off >= 1; off >>= 1) lsum += __shfl_xor(lsum, off, 64);
    const float lse = lmax + logf(lsum);
    #pragma unroll
    for (int kk = 0; kk < 5; ++kk) { int d = lane + kk*64; if (d < OUT) agg[rowoff+d] = v[kk]-lse; }
}

// ===========================================================================
extern "C" void kernel_launch(void* const* d_in, const int* in_sizes, int n_in,
                              void* d_out, int out_size, void* d_ws, size_t ws_size,
                              hipStream_t stream) {
    const int*   edge_index = (const int*)d_in[0];   // [2, E]
    const int*   edge_type  = (const int*)d_in[1];   // [E]
    const float* basis      = (const float*)d_in[3]; // [B, N, OUT]
    const float* comp       = (const float*)d_in[4]; // [R, B]
    const float* root       = (const float*)d_in[5]; // [N, OUT]
    const float* bias       = (const float*)d_in[6]; // [OUT]

    // ws layout (aligned)
    const size_t o_part   = 0;            // int[N]   (scanA partial)
    const size_t o_cursor = 200192;       // int[N]   (deg, then scatter cursor)
    const size_t o_bsum   = 400384;       // int[256]
    const size_t o_offsF  = 401408;       // int[N+1] (final offsets)
    const size_t o_sorted = 601600;       // int[E]
    const size_t o_Wm     = 3801600;      // unsigned[5*N*64] = 64 MB (256B rows)
    const size_t o_Wt     = 67801600;     // unsigned[5*N*11] = 11 MB
    const size_t need     = o_Wt + (size_t)N_REL * N_NODES * 11 * sizeof(unsigned);

    if (ws_size >= need) {
        int*      part   = (int*)((char*)d_ws + o_part);
        int*      cursor = (int*)((char*)d_ws + o_cursor);
        int*      bsum   = (int*)((char*)d_ws + o_bsum);
        int*      offsF  = (int*)((char*)d_ws + o_offsF);
        int*      sorted = (int*)((char*)d_ws + o_sorted);
        unsigned* Wm     = (unsigned*)((char*)d_ws + o_Wm);
        unsigned* Wt     = (unsigned*)((char*)d_ws + o_Wt);

        rgcn_zero<<<NBLK, 256, 0, stream>>>(cursor, N_NODES);
        // 7325 blocks -> grid-stride W loop runs ~2.00 balanced passes
        rgcn_build_w_hist<<<7325, 256, 0, stream>>>(basis, comp,
                                                    edge_index + N_EDGES,
                                                    Wm, Wt, cursor);
        rgcn_scanA<<<NBLK, 256, 0, stream>>>(cursor, part, bsum);
        rgcn_scanBC<<<NBLK, 256, 0, stream>>>(part, bsum, offsF, cursor);
        rgcn_scatter<<<1024, 256, 0, stream>>>(edge_index, edge_index + N_EDGES,
                                               edge_type, cursor, sorted);
        rgcn_aggregate<<<(N_NODES + 3) / 4, 256, 0, stream>>>(
            offsF, sorted, Wm, Wt, root, bias, (float*)d_out);
    } else {
        float* agg = (float*)d_out;
        float* cnt = (float*)d_ws;
        hipMemsetAsync(agg, 0, (size_t)out_size * sizeof(float), stream);
        hipMemsetAsync(cnt, 0, (size_t)N_NODES * sizeof(float), stream);
        rgcn_edge_scatter<<<4096, 256, 0, stream>>>(edge_index, edge_type, basis,
                                                    comp, agg, cnt);
        const int blocks = (N_NODES + 3) / 4;
        rgcn_finalize<<<blocks, 256, 0, stream>>>(agg, cnt, root, bias);
    }
}